// Round 7
// baseline (195.251 us; speedup 1.0000x reference)
//
#include <hip/hip_runtime.h>
#include <stdint.h>

// Problem constants (fixed by reference setup_inputs)
#define BB 2
#define NN 16384
#define MM 4096
#define CC 64
#define KK 16
#define NQ (BB * MM)

// kNN config: one query per wave, 4 waves/block, all state wave-private
#define NBIN 512         // 1/32-octave bins over d^2 in [2^-8, 2^8]
#define SHIFT 18
#define BOFF 12000       // fkey(2^-8) >> 18
#define CAP 192          // per-query collect capacity (proven R5/R6)

// Spatial grid
#define G 32
#define GC (G * G * G)   // 32768 cells per batch
#define GLO (-4.0f)
#define GEDGE 0.25f
#define GINV 4.0f

typedef unsigned long long u64;

static __device__ __forceinline__ unsigned fkey(float d) {
    unsigned u = __float_as_uint(d);
    return u ^ (unsigned)(((int)u >> 31) | (int)0x80000000u);
}

static __device__ __forceinline__ int cellc(float x) {
    int v = (int)floorf((x - GLO) * GINV);
    return v < 0 ? 0 : (v > G - 1 ? G - 1 : v);
}

// RNE fp32 -> bf16 pair packed into one uint (lo = a, hi = b)
static __device__ __forceinline__ unsigned pack_bf16(float a, float b) {
    unsigned ua = __float_as_uint(a), ub = __float_as_uint(b);
    ua = (ua + 0x7fffu + ((ua >> 16) & 1u)) >> 16;
    ub = (ub + 0x7fffu + ((ub >> 16) & 1u)) & 0xffff0000u;
    return ua | ub;
}

// ---------- prep: [0,512) transpose x1 -> bf16 xt; [512,544) pts4 AoS + cell counts ----------
__global__ __launch_bounds__(256)
void prep_kernel(const float* __restrict__ p1, const float* __restrict__ x1,
                 float4* __restrict__ pts4, unsigned* __restrict__ xt32,
                 int* __restrict__ counts, int use_grid) {
    const int t = threadIdx.x;
    if (blockIdx.x >= 512) {
        int u = (blockIdx.x - 512) * 256 + t;          // 8192 threads, 4 pts each
        const float4* src = (const float4*)(p1 + (size_t)u * 12);
        float4 a = src[0], b = src[1], c = src[2];
        float px[4] = {a.x, a.w, b.z, c.y};
        float py[4] = {a.y, b.x, b.w, c.z};
        float pz[4] = {a.z, b.y, c.x, c.w};
        #pragma unroll
        for (int k = 0; k < 4; ++k) {
            float n = fmaf(px[k], px[k], fmaf(py[k], py[k], pz[k] * pz[k]));
            pts4[u * 4 + k] = make_float4(px[k], py[k], pz[k], n);
            if (use_grid) {
                int gp = u * 4 + k;
                int bb = gp >> 14;
                int cc = (cellc(px[k]) << 10) + (cellc(py[k]) << 5) + cellc(pz[k]);
                atomicAdd(&counts[bb * GC + cc], 1);
            }
        }
        return;
    }
    // transpose tile: x1 (B,C,N) f32 -> xt (B,N,C) bf16
    __shared__ float lds[64 * 65];
    const int bi = blockIdx.x;
    const int b  = bi >> 8;
    const int n0 = (bi & 255) << 6;
    const float* src = x1 + (size_t)b * CC * NN;
    #pragma unroll
    for (int r = 0; r < 16; ++r) {
        int c = r * 4 + (t >> 6);
        int n = t & 63;
        lds[n * 65 + c] = src[(size_t)c * NN + n0 + n];
    }
    __syncthreads();
    unsigned* dst = xt32 + ((size_t)b * NN + n0) * 32;
    #pragma unroll
    for (int r = 0; r < 8; ++r) {
        int idx = r * 256 + t;
        int n = idx >> 5, cu = idx & 31;
        dst[(size_t)n * 32 + cu] =
            pack_bf16(lds[n * 65 + cu * 2], lds[n * 65 + cu * 2 + 1]);
    }
}

// ---------- exclusive prefix over 32768 cell counts per batch ----------
__global__ __launch_bounds__(1024)
void scan_kernel(const int* __restrict__ counts, int* __restrict__ Sarr) {
    __shared__ int psum[16];
    const int b = blockIdx.x;
    const int t = threadIdx.x;
    const int l = t & 63, w = t >> 6;
    const int* cb = counts + b * GC;
    int* Sb = Sarr + b * (GC + 1);
    int loc[32]; int s = 0;
    const int base = t * 32;
    #pragma unroll
    for (int i = 0; i < 32; ++i) { loc[i] = cb[base + i]; s += loc[i]; }
    int pre = s;
    #pragma unroll
    for (int off = 1; off < 64; off <<= 1) {
        int o = __shfl_up(pre, off, 64);
        if (l >= off) pre += o;
    }
    if (l == 63) psum[w] = pre;
    int excl_in_wave = pre - s;
    __syncthreads();
    if (w == 0 && l < 16) {
        int v = psum[l];
        int p2 = v;
        #pragma unroll
        for (int off = 1; off < 16; off <<= 1) {
            int o = __shfl_up(p2, off, 64);
            if (l >= off) p2 += o;
        }
        psum[l] = p2 - v;
    }
    __syncthreads();
    int run = psum[w] + excl_in_wave;
    #pragma unroll
    for (int i = 0; i < 32; ++i) { Sb[1 + base + i] = run; run += loc[i]; }
    if (t == 0) Sb[0] = 0;
}

// ---------- scatter points into cell-sorted order ----------
__global__ __launch_bounds__(256)
void scatter_kernel(const float4* __restrict__ pts4, int* __restrict__ Sarr,
                    float4* __restrict__ sorted4, int* __restrict__ sidx) {
    int u = blockIdx.x * 256 + threadIdx.x;            // 32768 points
    float4 p = pts4[u];
    int b = u >> 14, n = u & (NN - 1);
    int c = (cellc(p.x) << 10) + (cellc(p.y) << 5) + cellc(p.z);
    int pos = atomicAdd(&Sarr[b * (GC + 1) + 1 + c], 1);
    sorted4[b * NN + pos] = p;
    sidx[b * NN + pos] = n;
}

// ---------- fused kNN: bound -> pruned scan -> select -> gather ----------
__global__ __launch_bounds__(256, 8)
void knn_kernel(const float4* __restrict__ pts4, const float* __restrict__ p2,
                const unsigned* __restrict__ xt32,
                const float4* __restrict__ sorted4, const int* __restrict__ sidx,
                const int* __restrict__ Sarr, float* __restrict__ out,
                int use_grid) {
    __shared__ unsigned hist[4][NBIN];     // 8 KB
    __shared__ u64 col[4][CAP];            // 6 KB
    __shared__ unsigned colcnt[4];
    __shared__ int sel[4][KK];
    __shared__ float fmean[4][CC];

    const int t = threadIdx.x;
    const int w = t >> 6;                  // wave = one query
    const int l = t & 63;
    const int qb = blockIdx.x * 4;
    const int q  = qb + w;
    const int b  = q >> 12;
    const float4* P = pts4 + (size_t)b * NN;

    const float qx = p2[q * 3], qy = p2[q * 3 + 1], qz = p2[q * 3 + 2];
    const float qn = fmaf(qx, qx, fmaf(qy, qy, qz * qz));

    #pragma unroll
    for (int i = 0; i < NBIN / 64; ++i) hist[w][i * 64 + l] = 0u;
    if (l == 0) colcnt[w] = 0u;
    // all hist/col state is wave-private: no block barrier needed until epilogue

    // ---- phase 1: first 4096 points (orig order, random sample) -> histogram ----
    #pragma unroll 4
    for (int it = 0; it < 64; ++it) {
        float4 pt = P[it * 64 + l];
        float d = fmaf(-2.0f, fmaf(qx, pt.x, fmaf(qy, pt.y, qz * pt.z)), qn + pt.w);
        int bin = (int)(fkey(d) >> SHIFT) - BOFF;
        bin = bin < 0 ? 0 : (bin > NBIN - 1 ? NBIN - 1 : bin);
        atomicAdd(&hist[w][bin], 1u);
    }

    // ---- beta: smallest bin with inclusive cum >= 16 (wave-private) ----
    float bnd;
    {
        unsigned c8[8], s = 0;
        #pragma unroll
        for (int i = 0; i < 8; ++i) { c8[i] = hist[w][l * 8 + i]; s += c8[i]; }
        unsigned pre = s;
        #pragma unroll
        for (int off = 1; off < 64; off <<= 1) {
            unsigned o = __shfl_up(pre, off, 64);
            if (l >= off) pre += o;
        }
        unsigned excl = pre - s;
        int bsel = 0x7fffffff;
        if (excl < KK) {
            unsigned cum = excl;
            #pragma unroll
            for (int i = 0; i < 8; ++i) {
                if (cum < KK && cum + c8[i] >= KK) bsel = l * 8 + i;
                cum += c8[i];
            }
        }
        #pragma unroll
        for (int off = 32; off; off >>= 1) {
            int o = __shfl_xor(bsel, off, 64);
            bsel = o < bsel ? o : bsel;
        }
        if (bsel == 0x7fffffff) bsel = NBIN - 1;
        bnd = __uint_as_float((((unsigned)(bsel + BOFF + 1)) << SHIFT) & 0x7fffffffu);
    }

    // ---- phase 2: collect d < bnd ----
    #define PUSH(dv, id)                                                        \
    {   unsigned key = fkey(dv);                                                \
        unsigned slot = atomicAdd(&colcnt[w], 1u);                              \
        slot = slot < CAP ? slot : CAP - 1;                                     \
        col[w][slot] = ((u64)key << 32) | (unsigned)(id); }

    if (use_grid) {
        const float R = sqrtf(bnd);
        const int x0 = cellc(qx - R), x1 = cellc(qx + R);
        const int y0 = cellc(qy - R), y1 = cellc(qy + R);
        const int z0 = cellc(qz - R), z1 = cellc(qz + R);
        const int* Sb = Sarr + b * (GC + 1);
        const float4* Q4 = sorted4 + (size_t)b * NN;
        const int* I4 = sidx + (size_t)b * NN;
        for (int ix = x0; ix <= x1; ++ix) {
            float clo = GLO + ix * GEDGE;
            float dx = fmaxf(0.f, fmaxf(clo - qx, qx - (clo + GEDGE)));
            float dx2 = dx * dx;
            if (dx2 > bnd) continue;
            for (int iy = y0; iy <= y1; ++iy) {
                float ylo = GLO + iy * GEDGE;
                float dy = fmaxf(0.f, fmaxf(ylo - qy, qy - (ylo + GEDGE)));
                if (fmaf(dy, dy, dx2) > bnd) continue;
                int cA = (ix << 10) + (iy << 5) + z0;
                int s0 = Sb[cA];                   // post-scatter: start of cA
                int e0 = Sb[cA + (z1 - z0) + 1];   // end of cB (z-contiguous run)
                for (int p = s0 + l; p < e0; p += 64) {
                    float4 pt = Q4[p];
                    float d = fmaf(-2.0f, fmaf(qx, pt.x, fmaf(qy, pt.y, qz * pt.z)),
                                   qn + pt.w);
                    if (d < bnd) PUSH(d, I4[p])
                }
            }
        }
    } else {
        #pragma unroll 2
        for (int it = 0; it < 256; ++it) {
            int p = it * 64 + l;
            float4 pt = P[p];
            float d = fmaf(-2.0f, fmaf(qx, pt.x, fmaf(qy, pt.y, qz * pt.z)),
                           qn + pt.w);
            if (d < bnd) PUSH(d, p)
        }
    }
    #undef PUSH

    // ---- select: exact top-16 on (key, idx) lexicographic ----
    {
        unsigned cnt = colcnt[w]; cnt = cnt < CAP ? cnt : CAP;
        u64 v0 = ((unsigned)l       < cnt) ? col[w][l]       : ~0ull;
        u64 v1 = ((unsigned)l + 64  < cnt) ? col[w][l + 64]  : ~0ull;
        u64 v2 = ((unsigned)l + 128 < cnt) ? col[w][l + 128] : ~0ull;
        #pragma unroll 1
        for (int k = 0; k < KK; ++k) {
            u64 m = v0 < v1 ? v0 : v1;
            m = v2 < m ? v2 : m;
            #pragma unroll
            for (int off = 32; off; off >>= 1) {
                u64 o = __shfl_xor(m, off, 64);
                m = o < m ? o : m;
            }
            if (v0 == m) v0 = ~0ull;
            if (v1 == m) v1 = ~0ull;
            if (v2 == m) v2 = ~0ull;
            if (l == 0)
                sel[w][k] = (m == ~0ull) ? 0 : (int)(unsigned)(m & 0xFFFFFFFFull);
        }
    }

    // ---- fused gather from bf16 xt: one wave per query, 4-way k-split ----
    {
        const int cg = l & 15;
        const int h  = l >> 4;
        const unsigned* xb = xt32 + (size_t)b * NN * 32 + cg * 2;
        float a0 = 0.f, a1 = 0.f, a2 = 0.f, a3 = 0.f;
        #pragma unroll
        for (int k = 0; k < 4; ++k) {
            int n = sel[w][h * 4 + k];
            uint2 v = *(const uint2*)(xb + (size_t)n * 32);
            a0 += __uint_as_float(v.x << 16);
            a1 += __uint_as_float(v.x & 0xffff0000u);
            a2 += __uint_as_float(v.y << 16);
            a3 += __uint_as_float(v.y & 0xffff0000u);
        }
        a0 += __shfl_xor(a0, 16, 64); a0 += __shfl_xor(a0, 32, 64);
        a1 += __shfl_xor(a1, 16, 64); a1 += __shfl_xor(a1, 32, 64);
        a2 += __shfl_xor(a2, 16, 64); a2 += __shfl_xor(a2, 32, 64);
        a3 += __shfl_xor(a3, 16, 64); a3 += __shfl_xor(a3, 32, 64);
        if (h == 0) {
            fmean[w][cg * 4 + 0] = a0; fmean[w][cg * 4 + 1] = a1;
            fmean[w][cg * 4 + 2] = a2; fmean[w][cg * 4 + 3] = a3;
        }
    }
    __syncthreads();
    {
        const int m0 = qb & (MM - 1);
        const float sc = 1.0f / 16.0f;
        float* ob = out + (size_t)b * CC * MM;
        int c = t >> 2, qi2 = t & 3;
        ob[(size_t)c * MM + m0 + qi2] = fmean[qi2][c] * sc;
    }
}

extern "C" void kernel_launch(void* const* d_in, const int* in_sizes, int n_in,
                              void* d_out, int out_size, void* d_ws, size_t ws_size,
                              hipStream_t stream) {
    const float* p1 = (const float*)d_in[0];   // (B,N,3)
    const float* x1 = (const float*)d_in[1];   // (B,C,N)
    const float* p2 = (const float*)d_in[2];   // (B,M,3)
    float* out = (float*)d_out;                // (B,C,M)

    char* ws = (char*)d_ws;
    float4*   pts4    = (float4*)ws;                       // 512 KB
    unsigned* xt32    = (unsigned*)(ws + 524288);          // 4.19 MB
    float4*   sorted4 = (float4*)(ws + 4718592);           // 512 KB
    int*      sidx    = (int*)(ws + 5242880);              // 128 KB
    int*      Sarr    = (int*)(ws + 5373952);              // 262,152 B
    int*      counts  = (int*)(ws + 5636104);              // 256 KB
    const size_t need_grid = 5898248;
    const int use_grid = ws_size >= need_grid ? 1 : 0;

    if (use_grid)
        hipMemsetAsync(counts, 0, (size_t)BB * GC * sizeof(int), stream);
    prep_kernel<<<544, 256, 0, stream>>>(p1, x1, pts4, xt32, counts, use_grid);
    if (use_grid) {
        scan_kernel<<<BB, 1024, 0, stream>>>(counts, Sarr);
        scatter_kernel<<<BB * NN / 256, 256, 0, stream>>>(pts4, Sarr, sorted4, sidx);
    }
    knn_kernel<<<NQ / 4, 256, 0, stream>>>(pts4, p2, xt32, sorted4, sidx, Sarr,
                                           out, use_grid);
}

// Round 10
// 134.937 us; speedup vs baseline: 1.4470x; 1.4470x over previous
//
#include <hip/hip_runtime.h>
#include <stdint.h>

#define BB 2
#define NN 16384
#define MM 4096
#define CC 64
#define KK 16
#define NQ (BB * MM)

#define NBIN 512         // 1/32-octave bins over d^2
#define SHIFT 18
#define BOFF 12000       // fkey(2^-8) >> 18
#define CAP 192

// Spatial grid
#define G 32
#define GC (G * G * G)
#define GLO (-4.0f)
#define GEDGE 0.25f
#define GINV 4.0f

typedef unsigned long long u64;

static __device__ __forceinline__ unsigned fkey(float d) {
    unsigned u = __float_as_uint(d);
    return u ^ (unsigned)(((int)u >> 31) | (int)0x80000000u);
}

static __device__ __forceinline__ int cellc(float x) {
    int v = (int)floorf((x - GLO) * GINV);
    return v < 0 ? 0 : (v > G - 1 ? G - 1 : v);
}

static __device__ __forceinline__ unsigned pack_bf16(float a, float b) {
    unsigned ua = __float_as_uint(a), ub = __float_as_uint(b);
    ua = (ua + 0x7fffu + ((ua >> 16) & 1u)) >> 16;
    ub = (ub + 0x7fffu + ((ub >> 16) & 1u)) & 0xffff0000u;
    return ua | ub;
}

// ---------- prep (R7-proven): [0,512) transpose; [512,544) pts4 + cell counts ----------
__global__ __launch_bounds__(256)
void prep_kernel(const float* __restrict__ p1, const float* __restrict__ x1,
                 float4* __restrict__ pts4, unsigned* __restrict__ xt32,
                 int* __restrict__ counts) {
    const int t = threadIdx.x;
    if (blockIdx.x >= 512) {
        int u = (blockIdx.x - 512) * 256 + t;          // 8192 threads, 4 pts each
        const float4* src = (const float4*)(p1 + (size_t)u * 12);
        float4 a = src[0], b = src[1], c = src[2];
        float px[4] = {a.x, a.w, b.z, c.y};
        float py[4] = {a.y, b.x, b.w, c.z};
        float pz[4] = {a.z, b.y, c.x, c.w};
        #pragma unroll
        for (int k = 0; k < 4; ++k) {
            float n = fmaf(px[k], px[k], fmaf(py[k], py[k], pz[k] * pz[k]));
            pts4[u * 4 + k] = make_float4(px[k], py[k], pz[k], n);
            int gp = u * 4 + k;
            int bb = gp >> 14;
            int cc = (cellc(px[k]) << 10) + (cellc(py[k]) << 5) + cellc(pz[k]);
            atomicAdd(&counts[bb * GC + cc], 1);
        }
        return;
    }
    __shared__ float lds[64 * 65];
    const int bi = blockIdx.x;
    const int b  = bi >> 8;
    const int n0 = (bi & 255) << 6;
    const float* src = x1 + (size_t)b * CC * NN;
    #pragma unroll
    for (int r = 0; r < 16; ++r) {
        int c = r * 4 + (t >> 6);
        int n = t & 63;
        lds[n * 65 + c] = src[(size_t)c * NN + n0 + n];
    }
    __syncthreads();
    unsigned* dst = xt32 + ((size_t)b * NN + n0) * 32;
    #pragma unroll
    for (int r = 0; r < 8; ++r) {
        int idx = r * 256 + t;
        int n = idx >> 5, cu = idx & 31;
        dst[(size_t)n * 32 + cu] =
            pack_bf16(lds[n * 65 + cu * 2], lds[n * 65 + cu * 2 + 1]);
    }
}

// ---------- scan (R7-proven verbatim): exclusive prefix over 32768 counts ----------
__global__ __launch_bounds__(1024)
void scan_kernel(const int* __restrict__ counts, int* __restrict__ Sarr) {
    __shared__ int psum[16];
    const int b = blockIdx.x;
    const int t = threadIdx.x;
    const int l = t & 63, w = t >> 6;
    const int* cb = counts + b * GC;
    int* Sb = Sarr + b * (GC + 1);
    int loc[32]; int s = 0;
    const int base = t * 32;
    #pragma unroll
    for (int i = 0; i < 32; ++i) { loc[i] = cb[base + i]; s += loc[i]; }
    int pre = s;
    #pragma unroll
    for (int off = 1; off < 64; off <<= 1) {
        int o = __shfl_up(pre, off, 64);
        if (l >= off) pre += o;
    }
    if (l == 63) psum[w] = pre;
    int excl_in_wave = pre - s;
    __syncthreads();
    if (w == 0 && l < 16) {
        int v = psum[l];
        int p2 = v;
        #pragma unroll
        for (int off = 1; off < 16; off <<= 1) {
            int o = __shfl_up(p2, off, 64);
            if (l >= off) p2 += o;
        }
        psum[l] = p2 - v;
    }
    __syncthreads();
    int run = psum[w] + excl_in_wave;
    #pragma unroll
    for (int i = 0; i < 32; ++i) { Sb[1 + base + i] = run; run += loc[i]; }
    if (t == 0) Sb[0] = 0;
}

// ---------- scatter (R7-proven verbatim) ----------
__global__ __launch_bounds__(256)
void scatter_kernel(const float4* __restrict__ pts4, int* __restrict__ Sarr,
                    float4* __restrict__ sorted4, int* __restrict__ sidx) {
    int u = blockIdx.x * 256 + threadIdx.x;            // 32768 points
    float4 p = pts4[u];
    int b = u >> 14, n = u & (NN - 1);
    int c = (cellc(p.x) << 10) + (cellc(p.y) << 5) + cellc(p.z);
    int pos = atomicAdd(&Sarr[b * (GC + 1) + 1 + c], 1);
    sorted4[b * NN + pos] = p;
    sidx[b * NN + pos] = n;
}

// ---------- fused kNN: shared hist -> beta -> compacted grid walk -> select -> gather ----------
__global__ __launch_bounds__(256, 8)
void knn_kernel(const float4* __restrict__ pts4, const float* __restrict__ p2,
                const unsigned* __restrict__ xt32,
                const float4* __restrict__ sorted4, const int* __restrict__ sidx,
                const int* __restrict__ Sarr, float* __restrict__ out,
                int use_grid) {
    __shared__ unsigned hist[4][NBIN];     // 8 KB
    __shared__ u64 col[4][CAP];            // 6 KB
    __shared__ unsigned colcnt[4];
    __shared__ int sel[4][KK];
    __shared__ float fmean[4][CC];

    const int t = threadIdx.x;
    const int w = t >> 6;                  // wave = one query (for phases 2+)
    const int l = t & 63;
    const int qb = blockIdx.x * 4;
    const int q  = qb + w;
    const int b  = q >> 12;
    const float4* P = pts4 + (size_t)b * NN;

    float qx[4], qy[4], qz[4], qn[4];
    #pragma unroll
    for (int j = 0; j < 4; ++j) {
        qx[j] = p2[(qb + j) * 3];
        qy[j] = p2[(qb + j) * 3 + 1];
        qz[j] = p2[(qb + j) * 3 + 2];
        qn[j] = fmaf(qx[j], qx[j], fmaf(qy[j], qy[j], qz[j] * qz[j]));
    }
    const float qxo = p2[q * 3], qyo = p2[q * 3 + 1], qzo = p2[q * 3 + 2];
    const float qno = fmaf(qxo, qxo, fmaf(qyo, qyo, qzo * qzo));

    #pragma unroll
    for (int i = t; i < 4 * NBIN; i += 256) ((unsigned*)hist)[i] = 0u;
    if (t < 4) colcnt[t] = 0u;
    __syncthreads();

    // ---- phase 1 (shared): wave w scans [w*1024, w*1024+1024) for all 4 queries ----
    #pragma unroll 2
    for (int it = 0; it < 16; ++it) {
        float4 pt = P[w * 1024 + it * 64 + l];
        #pragma unroll
        for (int j = 0; j < 4; ++j) {
            float d = fmaf(-2.0f, fmaf(qx[j], pt.x, fmaf(qy[j], pt.y, qz[j] * pt.z)),
                           qn[j] + pt.w);
            int bin = (int)(fkey(d) >> SHIFT) - BOFF;
            bin = bin < 0 ? 0 : (bin > NBIN - 1 ? NBIN - 1 : bin);
            atomicAdd(&hist[j][bin], 1u);
        }
    }
    __syncthreads();

    // ---- beta for own query ----
    float bnd;
    {
        unsigned c8[8], s = 0;
        #pragma unroll
        for (int i = 0; i < 8; ++i) { c8[i] = hist[w][l * 8 + i]; s += c8[i]; }
        unsigned pre = s;
        #pragma unroll
        for (int off = 1; off < 64; off <<= 1) {
            unsigned o = __shfl_up(pre, off, 64);
            if (l >= off) pre += o;
        }
        unsigned excl = pre - s;
        int bsel = 0x7fffffff;
        if (excl < KK) {
            unsigned cum = excl;
            #pragma unroll
            for (int i = 0; i < 8; ++i) {
                if (cum < KK && cum + c8[i] >= KK) bsel = l * 8 + i;
                cum += c8[i];
            }
        }
        #pragma unroll
        for (int off = 32; off; off >>= 1) {
            int o = __shfl_xor(bsel, off, 64);
            bsel = o < bsel ? o : bsel;
        }
        if (bsel == 0x7fffffff) bsel = NBIN - 1;
        bnd = __uint_as_float((((unsigned)(bsel + BOFF + 1)) << SHIFT) & 0x7fffffffu);
    }

    // ---- phase 2: collect d < bnd ----
    #define PUSH(dv, id)                                                        \
    {   unsigned key = fkey(dv);                                                \
        unsigned slot = atomicAdd(&colcnt[w], 1u);                              \
        slot = slot < CAP ? slot : CAP - 1;                                     \
        col[w][slot] = ((u64)key << 32) | (unsigned)(id); }

    if (use_grid) {
        const float R = sqrtf(bnd) * 1.0001f + 1e-6f;
        const int x0 = cellc(qxo - R), x1 = cellc(qxo + R);
        const int y0 = cellc(qyo - R), y1 = cellc(qyo + R);
        const int z0 = cellc(qzo - R), z1 = cellc(qzo + R);
        const int nz = z1 - z0;
        const int ny = y1 - y0 + 1;
        const int nruns = (x1 - x0 + 1) * ny;
        const int* Sb = Sarr + b * (GC + 1);
        const float4* Q4 = sorted4 + (size_t)b * NN;
        const int* I4 = sidx + (size_t)b * NN;

        for (int cbase = 0; cbase < nruns; cbase += 64) {
            int r = cbase + l;
            int sa = 0, len = 0;
            if (r < nruns) {
                int rx = r / ny;
                int ix = x0 + rx, iy = y0 + (r - rx * ny);
                // slab distance; boundary cells extend to +-inf (clamped points)
                float xlo = GLO + ix * GEDGE;
                float dxm = fmaxf(0.f, fmaxf(ix == 0     ? -1.f : xlo - qxo,
                                             ix == G - 1 ? -1.f : qxo - (xlo + GEDGE)));
                float ylo = GLO + iy * GEDGE;
                float dym = fmaxf(0.f, fmaxf(iy == 0     ? -1.f : ylo - qyo,
                                             iy == G - 1 ? -1.f : qyo - (ylo + GEDGE)));
                if (fmaf(dxm, dxm, dym * dym) <= bnd) {
                    int cA = (ix << 10) + (iy << 5) + z0;
                    sa = Sb[cA];
                    len = Sb[cA + nz + 1] - sa;
                }
            }
            // wave prefix-sum -> dense candidate space [0,T)
            int pre = len;
            #pragma unroll
            for (int off = 1; off < 64; off <<= 1) {
                int o = __shfl_up(pre, off, 64);
                if (l >= off) pre += o;
            }
            const int T = __shfl(pre, 63, 64);
            const int ofs = pre - len;
            // FIX (R10): keep all 64 lanes active through every shuffle.
            // Previous version diverged on the last trip (i >= T lanes exited),
            // making ds_bpermute read from inactive lanes -> undefined data.
            const int nb = (T + 63) >> 6;
            for (int ib = 0; ib < nb; ++ib) {
                const int i = ib * 64 + l;
                int lo = 0;   // binary lifting: last run with ofs[run] <= i
                #pragma unroll
                for (int st = 32; st; st >>= 1) {
                    int cnd = lo + st;
                    int oc = __shfl(ofs, cnd, 64);
                    if (oc <= i) lo = cnd;
                }
                int p = __shfl(sa, lo, 64) + (i - __shfl(ofs, lo, 64));
                const bool valid = i < T;
                p = valid ? p : 0;
                float4 pt = Q4[p];
                float d = fmaf(-2.0f, fmaf(qxo, pt.x, fmaf(qyo, pt.y, qzo * pt.z)),
                               qno + pt.w);
                if (valid && d < bnd) PUSH(d, I4[p])
            }
        }
    } else {
        #pragma unroll 2
        for (int it = 0; it < 256; ++it) {
            int p = it * 64 + l;
            float4 pt = P[p];
            float d = fmaf(-2.0f, fmaf(qxo, pt.x, fmaf(qyo, pt.y, qzo * pt.z)),
                           qno + pt.w);
            if (d < bnd) PUSH(d, p)
        }
    }
    #undef PUSH

    // ---- select: exact top-16 on (key, idx) ----
    {
        unsigned cnt = colcnt[w]; cnt = cnt < CAP ? cnt : CAP;
        u64 v0 = ((unsigned)l       < cnt) ? col[w][l]       : ~0ull;
        u64 v1 = ((unsigned)l + 64  < cnt) ? col[w][l + 64]  : ~0ull;
        u64 v2 = ((unsigned)l + 128 < cnt) ? col[w][l + 128] : ~0ull;
        #pragma unroll 1
        for (int k = 0; k < KK; ++k) {
            u64 m = v0 < v1 ? v0 : v1;
            m = v2 < m ? v2 : m;
            #pragma unroll
            for (int off = 32; off; off >>= 1) {
                u64 o = __shfl_xor(m, off, 64);
                m = o < m ? o : m;
            }
            if (v0 == m) v0 = ~0ull;
            if (v1 == m) v1 = ~0ull;
            if (v2 == m) v2 = ~0ull;
            if (l == 0)
                sel[w][k] = (m == ~0ull) ? 0 : (int)(unsigned)(m & 0xFFFFFFFFull);
        }
    }

    // ---- fused gather from bf16 xt ----
    {
        const int cg = l & 15;
        const int h  = l >> 4;
        const unsigned* xb = xt32 + (size_t)b * NN * 32 + cg * 2;
        float a0 = 0.f, a1 = 0.f, a2 = 0.f, a3 = 0.f;
        #pragma unroll
        for (int k = 0; k < 4; ++k) {
            int n = sel[w][h * 4 + k];
            uint2 v = *(const uint2*)(xb + (size_t)n * 32);
            a0 += __uint_as_float(v.x << 16);
            a1 += __uint_as_float(v.x & 0xffff0000u);
            a2 += __uint_as_float(v.y << 16);
            a3 += __uint_as_float(v.y & 0xffff0000u);
        }
        a0 += __shfl_xor(a0, 16, 64); a0 += __shfl_xor(a0, 32, 64);
        a1 += __shfl_xor(a1, 16, 64); a1 += __shfl_xor(a1, 32, 64);
        a2 += __shfl_xor(a2, 16, 64); a2 += __shfl_xor(a2, 32, 64);
        a3 += __shfl_xor(a3, 16, 64); a3 += __shfl_xor(a3, 32, 64);
        if (h == 0) {
            fmean[w][cg * 4 + 0] = a0; fmean[w][cg * 4 + 1] = a1;
            fmean[w][cg * 4 + 2] = a2; fmean[w][cg * 4 + 3] = a3;
        }
    }
    __syncthreads();
    {
        const int m0 = qb & (MM - 1);
        const float sc = 1.0f / 16.0f;
        float* ob = out + (size_t)b * CC * MM;
        int c = t >> 2, qi2 = t & 3;
        ob[(size_t)c * MM + m0 + qi2] = fmean[qi2][c] * sc;
    }
}

extern "C" void kernel_launch(void* const* d_in, const int* in_sizes, int n_in,
                              void* d_out, int out_size, void* d_ws, size_t ws_size,
                              hipStream_t stream) {
    const float* p1 = (const float*)d_in[0];   // (B,N,3)
    const float* x1 = (const float*)d_in[1];   // (B,C,N)
    const float* p2 = (const float*)d_in[2];   // (B,M,3)
    float* out = (float*)d_out;                // (B,C,M)

    char* ws = (char*)d_ws;
    float4*   pts4    = (float4*)ws;                       // 512 KB
    unsigned* xt32    = (unsigned*)(ws + 524288);          // 4.19 MB
    float4*   sorted4 = (float4*)(ws + 4718592);           // 512 KB
    int*      sidx    = (int*)(ws + 5242880);              // 128 KB
    int*      Sarr    = (int*)(ws + 5373952);              // 262,152 B
    int*      counts  = (int*)(ws + 5636104);              // 262,144 B
    const size_t need_grid = 5898248;
    const int use_grid = ws_size >= need_grid ? 1 : 0;

    if (use_grid)
        hipMemsetAsync(counts, 0, (size_t)BB * GC * sizeof(int), stream);
    prep_kernel<<<544, 256, 0, stream>>>(p1, x1, pts4, xt32,
                                         use_grid ? counts : (int*)Sarr);
    if (use_grid) {
        scan_kernel<<<BB, 1024, 0, stream>>>(counts, Sarr);
        scatter_kernel<<<BB * NN / 256, 256, 0, stream>>>(pts4, Sarr, sorted4, sidx);
    }
    knn_kernel<<<NQ / 4, 256, 0, stream>>>(pts4, p2, xt32, sorted4, sidx, Sarr,
                                           out, use_grid);
}